// Round 1
// baseline (50.637 us; speedup 1.0000x reference)
//
#include <hip/hip_runtime.h>

// 3D median filter 3x3x3, stride 1, reflect padding, fp32.
// x: (2, 1, 160, 160, 160) -> same shape. Median = rank 13 (0-based) of 27.

#define DEV __device__ __forceinline__

DEV void ce(float& a, float& b) {
    float lo = fminf(a, b);
    float hi = fmaxf(a, b);
    a = lo; b = hi;
}

DEV void sort3(float& a, float& b, float& c) { ce(a, b); ce(a, c); ce(b, c); }

// Batcher odd-even merges of small sorted sequences.
DEV void merge21(float a0, float a1, float b0, float z[3]) {
    float e0 = a0, e1 = b0; ce(e0, e1);           // merge evens (a0),(b0)
    z[0] = e0; z[1] = a1; z[2] = e1; ce(z[1], z[2]);
}
DEV void merge22(float a0, float a1, float b0, float b1, float z[4]) {
    float p0 = a0, p1 = b0; ce(p0, p1);
    float q0 = a1, q1 = b1; ce(q0, q1);
    z[0] = p0; z[1] = q0; z[2] = p1; ce(z[1], z[2]); z[3] = q1;
}
DEV void merge31(float a0, float a1, float a2, float b0, float z[4]) {
    float e[3]; merge21(a0, a2, b0, e);
    z[0] = e[0]; z[1] = a1; z[2] = e[1]; ce(z[1], z[2]); z[3] = e[2];
}
DEV void merge32(float a0, float a1, float a2, float b0, float b1, float z[5]) {
    float e[3]; merge21(a0, a2, b0, e);
    float o0 = a1, o1 = b1; ce(o0, o1);
    z[0] = e[0];
    z[1] = o0; z[2] = e[1]; ce(z[1], z[2]);
    z[3] = o1; z[4] = e[2]; ce(z[3], z[4]);
}
DEV void merge33(const float a[3], const float b[3], float z[6]) {
    float e[4]; merge22(a[0], a[2], b[0], b[2], e);
    float o0 = a[1], o1 = b[1]; ce(o0, o1);
    z[0] = e[0];
    z[1] = o0; z[2] = e[1]; ce(z[1], z[2]);
    z[3] = o1; z[4] = e[2]; ce(z[3], z[4]);
    z[5] = e[3];
}
DEV void merge63(const float a[6], const float b[3], float z[9]) {
    float e[5]; merge32(a[0], a[2], a[4], b[0], b[2], e);
    float o[4]; merge31(a[1], a[3], a[5], b[1], o);
    z[0] = e[0];
    z[1] = o[0]; z[2] = e[1]; ce(z[1], z[2]);
    z[3] = o[1]; z[4] = e[2]; ce(z[3], z[4]);
    z[5] = o[2]; z[6] = e[3]; ce(z[5], z[6]);
    z[7] = o[3]; z[8] = e[4]; ce(z[7], z[8]);
}
DEV void merge44(const float a[4], const float b[4], float z[8]) {
    float e[4]; merge22(a[0], a[2], b[0], b[2], e);
    float o[4]; merge22(a[1], a[3], b[1], b[3], o);
    z[0] = e[0];
    z[1] = o[0]; z[2] = e[1]; ce(z[1], z[2]);
    z[3] = o[1]; z[4] = e[2]; ce(z[3], z[4]);
    z[5] = o[2]; z[6] = e[3]; ce(z[5], z[6]);
    z[7] = o[3];
}
DEV void merge55(const float a[5], const float b[5], float z[10]) {
    float ae[3] = {a[0], a[2], a[4]}, be[3] = {b[0], b[2], b[4]};
    float e[6]; merge33(ae, be, e);
    float o[4]; merge22(a[1], a[3], b[1], b[3], o);
    z[0] = e[0];
    z[1] = o[0]; z[2] = e[1]; ce(z[1], z[2]);
    z[3] = o[1]; z[4] = e[2]; ce(z[3], z[4]);
    z[5] = o[2]; z[6] = e[3]; ce(z[5], z[6]);
    z[7] = o[3]; z[8] = e[4]; ce(z[7], z[8]);
    z[9] = e[5];
}
DEV void merge99(const float a[9], const float b[9], float z[18]) {
    float ae[5] = {a[0], a[2], a[4], a[6], a[8]};
    float be[5] = {b[0], b[2], b[4], b[6], b[8]};
    float e[10]; merge55(ae, be, e);
    float ao[4] = {a[1], a[3], a[5], a[7]};
    float bo[4] = {b[1], b[3], b[5], b[7]};
    float o[8]; merge44(ao, bo, o);
    z[0] = e[0];
#pragma unroll
    for (int i = 0; i < 8; i++) {
        z[2 * i + 1] = o[i];
        z[2 * i + 2] = e[i + 1];
        ce(z[2 * i + 1], z[2 * i + 2]);
    }
    z[17] = e[9];
}

// Sorted 9 of the 3x3 (y,x) window of plane `pb`, offsets precomputed (reflect).
DEV void compute_m(const float* __restrict__ pb, const int off[9], float M[9]) {
    float r0[3] = {pb[off[0]], pb[off[1]], pb[off[2]]};
    float r1[3] = {pb[off[3]], pb[off[4]], pb[off[5]]};
    float r2[3] = {pb[off[6]], pb[off[7]], pb[off[8]]};
    sort3(r0[0], r0[1], r0[2]);
    sort3(r1[0], r1[1], r1[2]);
    sort3(r2[0], r2[1], r2[2]);
    float s6[6]; merge33(r0, r1, s6);
    merge63(s6, r2, M);
}

// median (rank 13 of 27) of three sorted 9-lists.
// E = merge(P,Q) sorted 18; selection identity over splits of 14:
//   med = min( E[13], max(R[i], E[12-i]) for i=0..8 )
// (E[0..3], E[14..17] are dead -> DCE prunes those compare-exchanges.)
DEV float median27(const float P[9], const float Q[9], const float R[9]) {
    float E[18]; merge99(P, Q, E);
    float m = E[13];
#pragma unroll
    for (int i = 0; i < 9; i++) m = fminf(m, fmaxf(R[i], E[12 - i]));
    return m;
}

constexpr int Bb = 2, Dd = 160, Hh = 160, Ww = 160;
constexpr int HW = Hh * Ww;          // 25600
constexpr int CH = 20;               // z-chunk per thread
constexpr int NCH = Dd / CH;         // 8 chunks
constexpr int TOTAL = Bb * NCH * HW; // 409600 threads

__global__ __launch_bounds__(256) void MedianPool3d_68994354642979_kernel(
    const float* __restrict__ in, float* __restrict__ out) {
    int tid = blockIdx.x * 256 + threadIdx.x;
    if (tid >= TOTAL) return;
    int t = tid % HW;
    int co = tid / HW;      // 0..15: (b, chunk)
    int b = co >> 3;        // co / NCH, NCH == 8
    int chunk = co & 7;     // co % NCH
    int y = t / Ww, x = t - y * Ww;

    // reflect (jnp.pad mode="reflect", pad=1): -1 -> 1, N -> N-2
    int ym = (y == 0) ? 1 : y - 1;
    int yp = (y == Hh - 1) ? Hh - 2 : y + 1;
    int xm = (x == 0) ? 1 : x - 1;
    int xp = (x == Ww - 1) ? Ww - 2 : x + 1;

    int off[9] = {ym * Ww + xm, ym * Ww + x, ym * Ww + xp,
                  y * Ww + xm,  y * Ww + x,  y * Ww + xp,
                  yp * Ww + xm, yp * Ww + x, yp * Ww + xp};

    const float* base = in + (size_t)b * Dd * HW;
    int z0 = chunk * CH;

    float Mp[9], Mc[9], Mn[9];
    int pm1 = (z0 == 0) ? 1 : z0 - 1; // reflect(z0-1)
    compute_m(base + (size_t)pm1 * HW, off, Mp);
    compute_m(base + (size_t)z0 * HW, off, Mc);

    for (int s = 0; s < CH; s++) {
        int z = z0 + s;
        int pn = z + 1;
        if (pn >= Dd) pn = 2 * Dd - 2 - pn; // reflect(160) = 158
        compute_m(base + (size_t)pn * HW, off, Mn);

        out[(size_t)(b * Dd + z) * HW + t] = median27(Mp, Mc, Mn);

#pragma unroll
        for (int k = 0; k < 9; k++) { Mp[k] = Mc[k]; Mc[k] = Mn[k]; }
    }
}

extern "C" void kernel_launch(void* const* d_in, const int* in_sizes, int n_in,
                              void* d_out, int out_size, void* d_ws, size_t ws_size,
                              hipStream_t stream) {
    const float* x = (const float*)d_in[0];
    float* out = (float*)d_out;
    constexpr int threads = 256;
    constexpr int blocks = TOTAL / threads; // 1600 exactly
    MedianPool3d_68994354642979_kernel<<<blocks, threads, 0, stream>>>(x, out);
}

// Round 3
// 31.512 us; speedup vs baseline: 1.6069x; 1.6069x over previous
//
#include <hip/hip_runtime.h>

// 3D median filter 3x3x3, stride 1, reflect padding.
// x: (2, 1, 160, 160, 160) fp32 -> same shape. Median = rank 13 (0-based) of 27.
// Packed-f16 version: each lane computes 2 x-adjacent outputs in a half2 via
// v_pk_min/max_f16; merge99 of the shared plane pair is reused by 2 z-outputs.

typedef __fp16 hf2 __attribute__((ext_vector_type(2)));

#define DEV __device__ __forceinline__

DEV hf2 hmin2(hf2 a, hf2 b) { return __builtin_elementwise_min(a, b); }
DEV hf2 hmax2(hf2 a, hf2 b) { return __builtin_elementwise_max(a, b); }
DEV void ce(hf2& a, hf2& b) { hf2 lo = hmin2(a, b); hf2 hi = hmax2(a, b); a = lo; b = hi; }
DEV hf2 pk2(float a, float b) { return __builtin_amdgcn_cvt_pkrtz(a, b); }

DEV void sort3(hf2& a, hf2& b, hf2& c) { ce(a, b); ce(a, c); ce(b, c); }

// Batcher odd-even merges of small sorted sequences (same networks verified
// exact in round 1).
DEV void merge21(hf2 a0, hf2 a1, hf2 b0, hf2 z[3]) {
    hf2 e0 = a0, e1 = b0; ce(e0, e1);
    z[0] = e0; z[1] = a1; z[2] = e1; ce(z[1], z[2]);
}
DEV void merge22(hf2 a0, hf2 a1, hf2 b0, hf2 b1, hf2 z[4]) {
    hf2 p0 = a0, p1 = b0; ce(p0, p1);
    hf2 q0 = a1, q1 = b1; ce(q0, q1);
    z[0] = p0; z[1] = q0; z[2] = p1; ce(z[1], z[2]); z[3] = q1;
}
DEV void merge31(hf2 a0, hf2 a1, hf2 a2, hf2 b0, hf2 z[4]) {
    hf2 e[3]; merge21(a0, a2, b0, e);
    z[0] = e[0]; z[1] = a1; z[2] = e[1]; ce(z[1], z[2]); z[3] = e[2];
}
DEV void merge32(hf2 a0, hf2 a1, hf2 a2, hf2 b0, hf2 b1, hf2 z[5]) {
    hf2 e[3]; merge21(a0, a2, b0, e);
    hf2 o0 = a1, o1 = b1; ce(o0, o1);
    z[0] = e[0];
    z[1] = o0; z[2] = e[1]; ce(z[1], z[2]);
    z[3] = o1; z[4] = e[2]; ce(z[3], z[4]);
}
DEV void merge33(const hf2 a[3], const hf2 b[3], hf2 z[6]) {
    hf2 e[4]; merge22(a[0], a[2], b[0], b[2], e);
    hf2 o0 = a[1], o1 = b[1]; ce(o0, o1);
    z[0] = e[0];
    z[1] = o0; z[2] = e[1]; ce(z[1], z[2]);
    z[3] = o1; z[4] = e[2]; ce(z[3], z[4]);
    z[5] = e[3];
}
DEV void merge63(const hf2 a[6], const hf2 b[3], hf2 z[9]) {
    hf2 e[5]; merge32(a[0], a[2], a[4], b[0], b[2], e);
    hf2 o[4]; merge31(a[1], a[3], a[5], b[1], o);
    z[0] = e[0];
    z[1] = o[0]; z[2] = e[1]; ce(z[1], z[2]);
    z[3] = o[1]; z[4] = e[2]; ce(z[3], z[4]);
    z[5] = o[2]; z[6] = e[3]; ce(z[5], z[6]);
    z[7] = o[3]; z[8] = e[4]; ce(z[7], z[8]);
}
DEV void merge44(const hf2 a[4], const hf2 b[4], hf2 z[8]) {
    hf2 e[4]; merge22(a[0], a[2], b[0], b[2], e);
    hf2 o[4]; merge22(a[1], a[3], b[1], b[3], o);
    z[0] = e[0];
    z[1] = o[0]; z[2] = e[1]; ce(z[1], z[2]);
    z[3] = o[1]; z[4] = e[2]; ce(z[3], z[4]);
    z[5] = o[2]; z[6] = e[3]; ce(z[5], z[6]);
    z[7] = o[3];
}
DEV void merge55(const hf2 a[5], const hf2 b[5], hf2 z[10]) {
    hf2 ae[3] = {a[0], a[2], a[4]}, be[3] = {b[0], b[2], b[4]};
    hf2 e[6]; merge33(ae, be, e);
    hf2 o[4]; merge22(a[1], a[3], b[1], b[3], o);
    z[0] = e[0];
    z[1] = o[0]; z[2] = e[1]; ce(z[1], z[2]);
    z[3] = o[1]; z[4] = e[2]; ce(z[3], z[4]);
    z[5] = o[2]; z[6] = e[3]; ce(z[5], z[6]);
    z[7] = o[3]; z[8] = e[4]; ce(z[7], z[8]);
    z[9] = e[5];
}
DEV void merge99(const hf2 a[9], const hf2 b[9], hf2 z[18]) {
    hf2 ae[5] = {a[0], a[2], a[4], a[6], a[8]};
    hf2 be[5] = {b[0], b[2], b[4], b[6], b[8]};
    hf2 e[10]; merge55(ae, be, e);
    hf2 ao[4] = {a[1], a[3], a[5], a[7]};
    hf2 bo[4] = {b[1], b[3], b[5], b[7]};
    hf2 o[8]; merge44(ao, bo, o);
    z[0] = e[0];
#pragma unroll
    for (int i = 0; i < 8; i++) {
        z[2 * i + 1] = o[i];
        z[2 * i + 2] = e[i + 1];
        ce(z[2 * i + 1], z[2 * i + 2]);
    }
    z[17] = e[9];
}

// Sorted 9 (packed x2) of the 3x3 (y,x) window of plane `pb`.
DEV void compute_m(const float* __restrict__ pb, const int ro[3], int c0, int x0, int c3,
                   hf2 M[9]) {
    hf2 r[3][3];
#pragma unroll
    for (int i = 0; i < 3; i++) {
        const float* p = pb + ro[i];
        float a = p[c0];
        float2 bc = *reinterpret_cast<const float2*>(p + x0);  // 8B-aligned (x0 even)
        float d = p[c3];
        r[i][0] = pk2(a, bc.x);      // left taps of (x0, x0+1)
        r[i][1] = pk2(bc.x, bc.y);   // center taps
        r[i][2] = pk2(bc.y, d);      // right taps
    }
    sort3(r[0][0], r[0][1], r[0][2]);
    sort3(r[1][0], r[1][1], r[1][2]);
    sort3(r[2][0], r[2][1], r[2][2]);
    hf2 s6[6]; merge33(r[0], r[1], s6);
    merge63(s6, r[2], M);
}

// rank-13-of-27 from merged-18 E and sorted-9 R:
//   med = min(E[13], min_i max(R[i], E[12-i]))   (verified exact in round 1)
DEV hf2 sel13(const hf2 E[18], const hf2 R[9]) {
    hf2 m = E[13];
#pragma unroll
    for (int i = 0; i < 9; i++) m = hmin2(m, hmax2(R[i], E[12 - i]));
    return m;
}

constexpr int Bb = 2, Dd = 160, Hh = 160, Ww = 160;
constexpr int HW = Hh * Ww;           // 25600
constexpr int WP = Ww / 2;            // 80 packed-x pairs
constexpr int TP = Hh * WP;           // 12800 threads per (b, chunk)
constexpr int CH = 10;                // z-chunk per thread
constexpr int NCH = Dd / CH;          // 16
constexpr int TOTAL = Bb * NCH * TP;  // 409600

__global__ __launch_bounds__(256) void MedianPool3d_68994354642979_kernel(
    const float* __restrict__ in, float* __restrict__ out) {
    int tid = blockIdx.x * 256 + threadIdx.x;
    if (tid >= TOTAL) return;
    int t = tid % TP;
    int co = tid / TP;
    int b = co >> 4;       // / NCH (16)
    int chunk = co & 15;   // % NCH
    int y = t / WP;
    int px = t - y * WP;
    int x0 = px * 2;

    // reflect padding (jnp.pad mode="reflect", pad=1)
    int ym = (y == 0) ? 1 : y - 1;
    int yp = (y == Hh - 1) ? Hh - 2 : y + 1;
    int ro[3] = {ym * Ww, y * Ww, yp * Ww};
    int c0 = (x0 == 0) ? 1 : x0 - 1;               // left tap of x0
    int c3 = (x0 == Ww - 2) ? (Ww - 2) : x0 + 2;   // right tap of x0+1

    const float* base = in + (size_t)b * Dd * HW;
    float* ob = out + (size_t)b * Dd * HW;
    int z0 = chunk * CH;

    auto planeptr = [&](int p) {
        if (p < 0) p = -p;                 // reflect(-1) = 1
        if (p >= Dd) p = 2 * Dd - 2 - p;   // reflect(160) = 158
        return base + (size_t)p * HW;
    };

    // Ring buffer of sorted-9 plane windows. Plane q = z - (z0-1); slot = q & 3.
    hf2 SS[4][9];
    compute_m(planeptr(z0 - 1), ro, c0, x0, c3, SS[0]);
    compute_m(planeptr(z0),     ro, c0, x0, c3, SS[1]);
    compute_m(planeptr(z0 + 1), ro, c0, x0, c3, SS[2]);

#pragma unroll
    for (int j = 0; j < CH / 2; j++) {
        int z = z0 + 2 * j;
        int sm1 = (2 * j) & 3;      // S[z-1]
        int s0  = (2 * j + 1) & 3;  // S[z]
        int s1  = (2 * j + 2) & 3;  // S[z+1]
        int s2  = (2 * j + 3) & 3;  // S[z+2]

        compute_m(planeptr(z + 2), ro, c0, x0, c3, SS[s2]);

        hf2 E[18];
        merge99(SS[s0], SS[s1], E);       // shared pair (z, z+1) -> used twice
        hf2 med0 = sel13(E, SS[sm1]);     // output z   : third plane z-1
        hf2 med1 = sel13(E, SS[s2]);      // output z+1 : third plane z+2

        float* o0 = ob + (size_t)z * HW + ro[1] + x0;
        float* o1 = o0 + HW;
        *reinterpret_cast<float2*>(o0) = make_float2((float)med0[0], (float)med0[1]);
        *reinterpret_cast<float2*>(o1) = make_float2((float)med1[0], (float)med1[1]);

        if (j < CH / 2 - 1)  // prefetch S[z+3] into the retired slot
            compute_m(planeptr(z + 3), ro, c0, x0, c3, SS[sm1]);
    }
}

extern "C" void kernel_launch(void* const* d_in, const int* in_sizes, int n_in,
                              void* d_out, int out_size, void* d_ws, size_t ws_size,
                              hipStream_t stream) {
    const float* x = (const float*)d_in[0];
    float* out = (float*)d_out;
    constexpr int threads = 256;
    constexpr int blocks = TOTAL / threads;  // 1600 exactly
    MedianPool3d_68994354642979_kernel<<<blocks, threads, 0, stream>>>(x, out);
}